// Round 1
// baseline (1430.510 us; speedup 1.0000x reference)
//
#include <hip/hip_runtime.h>
#include <math.h>

#define HW25600 25600
#define DIM 128
#define NPIX 409600
#define KCAND 100
#define RPAD 128
#define DSW 3200              // u32 words per downsampled row-mask (320*320 bits)
#define MOUT 40960000         // masks output elements (100*640*640)

// ---- workspace byte offsets ----
#define WS_TOPV    0          // f32[128] top_s
#define WS_TOPI    512        // i32[128] indices
#define WS_VALID   1024       // f32[128]
#define WS_KEEPF   1536       // f32[128]
#define WS_MNT     2048       // f32[128*128] mn, layout [d][r]
#define WS_META    67584      // f32[128*128] meta, layout [r][d]
#define WS_CNT     133120     // f64[128] seg pixel counts
#define WS_SSUM    134144     // f64[128] seg score sums
#define WS_INTER   135168     // f32[100*100] downsampled mask intersections
#define WS_MN2T    175168     // f32[128*128] permuted mn, layout [d][r]
#define WS_SCALE2  240704     // f32[128] final row scales (keep2)
#define WS_DS      241216     // u32[128*3200] bitpacked downsampled masks
// total: 1,879,616 bytes

__device__ __forceinline__ unsigned int spread16(unsigned int x) {
  x &= 0xFFFFu;
  x = (x | (x << 8)) & 0x00FF00FFu;
  x = (x | (x << 4)) & 0x0F0F0F0Fu;
  x = (x | (x << 2)) & 0x33333333u;
  x = (x | (x << 1)) & 0x55555555u;
  return x;
}

// ============ kernel 1: sigmoid + top-100 (radix histogram select) ============
__global__ __launch_bounds__(256) void topk_kernel(const float* __restrict__ pred, char* ws) {
  float* topv   = (float*)(ws + WS_TOPV);
  int*   topi   = (int*)(ws + WS_TOPI);
  float* validf = (float*)(ws + WS_VALID);
  double* cntd  = (double*)(ws + WS_CNT);
  double* ssumd = (double*)(ws + WS_SSUM);

  __shared__ unsigned int hist[1024];
  __shared__ float cv[1024];
  __shared__ int ci[1024];
  __shared__ int scl[4];
  __shared__ unsigned int ncand;

  int tid = threadIdx.x;
  // zero f64 stat accumulators for the GEMM pass (ws is poisoned 0xAA)
  for (int r = tid; r < RPAD; r += 256) { cntd[r] = 0.0; ssumd[r] = 0.0; }
  for (int b = tid; b < 1024; b += 256) hist[b] = 0;
  if (tid == 0) ncand = 0;
  __syncthreads();

  // pass A: histogram on bits[30:21] (sigmoid in (0,1) -> positive floats, monotone bits)
  for (int k = tid; k < HW25600; k += 256) {
    float s = 1.0f / (1.0f + expf(-pred[k]));
    unsigned int u = __float_as_uint(s);
    atomicAdd(&hist[u >> 21], 1u);
  }
  __syncthreads();
  if (tid == 0) {
    int c = 0, B = 0;
    for (int b = 1023; b >= 0; --b) {
      int h = (int)hist[b];
      if (c + h >= KCAND) { B = b; break; }
      c += h;
    }
    scl[0] = B; scl[1] = c;
  }
  __syncthreads();
  int B = scl[0], cAb = scl[1];
  __syncthreads();
  for (int b = tid; b < 1024; b += 256) hist[b] = 0;
  __syncthreads();
  // pass B: refine within bin B on bits[20:11]
  for (int k = tid; k < HW25600; k += 256) {
    float s = 1.0f / (1.0f + expf(-pred[k]));
    unsigned int u = __float_as_uint(s);
    if ((int)(u >> 21) == B) atomicAdd(&hist[(u >> 11) & 1023], 1u);
  }
  __syncthreads();
  if (tid == 0) {
    int target = KCAND - cAb;
    int c = 0, B2 = 0;
    for (int b = 1023; b >= 0; --b) {
      int h = (int)hist[b];
      if (c + h >= target) { B2 = b; break; }
      c += h;
    }
    scl[2] = B2;
  }
  __syncthreads();
  unsigned int thr = ((unsigned int)B << 21) | ((unsigned int)scl[2] << 11);
  // pass C: collect candidates (superset of top-100, ~100-110 expected)
  for (int k = tid; k < HW25600; k += 256) {
    float s = 1.0f / (1.0f + expf(-pred[k]));
    unsigned int u = __float_as_uint(s);
    if (u >= thr) {
      unsigned int slot = atomicAdd(&ncand, 1u);
      if (slot < 1024u) { cv[slot] = s; ci[slot] = k; }
    }
  }
  __syncthreads();
  int nc = (int)(ncand < 1024u ? ncand : 1024u);
  // pass D: exact rank (descending value, ascending index on ties) == lax.top_k order
  for (int c = tid; c < nc; c += 256) {
    float v = cv[c]; int id = ci[c];
    int rk = 0;
    for (int o = 0; o < nc; ++o) {
      float u2 = cv[o]; int i2 = ci[o];
      rk += (int)((u2 > v) || (u2 == v && i2 < id));
    }
    if (rk < KCAND) {
      topv[rk] = v; topi[rk] = id;
      validf[rk] = (v > 0.75f) ? 1.0f : 0.0f;
    }
  }
  for (int r = tid; r < RPAD; r += 256)
    if (r >= KCAND) { topv[r] = 0.0f; topi[r] = 0; validf[r] = 0.0f; }
}

// ============ kernel 2: feat gather, cosine sim, dedup, meta kernels, mn ============
__global__ __launch_bounds__(256) void fuse_kernel(const float* __restrict__ emb, char* ws) {
  float* topv   = (float*)(ws + WS_TOPV);
  int*   topi   = (int*)(ws + WS_TOPI);
  float* validfg= (float*)(ws + WS_VALID);
  float* keepfg = (float*)(ws + WS_KEEPF);
  float* mnt    = (float*)(ws + WS_MNT);
  float* metag  = (float*)(ws + WS_META);
  (void)topv;

  __shared__ float feat_s[KCAND * DIM];      // 51200 B
  __shared__ unsigned int lab[KCAND * 4];
  __shared__ unsigned int lkb[KCAND * 4];
  __shared__ float rinv[KCAND];
  __shared__ float valids[KCAND];
  __shared__ float keeps[KCAND];
  __shared__ float divis[KCAND];
  __shared__ float mnrm[KCAND];

  int tid = threadIdx.x;
  for (int t = tid; t < KCAND * 4; t += 256) { lab[t] = 0u; lkb[t] = 0u; }
  for (int i = tid; i < KCAND; i += 256) valids[i] = validfg[i];
  for (int t = tid; t < KCAND * DIM; t += 256) {
    int i = t >> 7, d = t & 127;
    feat_s[t] = emb[d * HW25600 + topi[i]];
  }
  __syncthreads();
  for (int i = tid; i < KCAND; i += 256) {
    float n2 = 0.0f;
    for (int d = 0; d < DIM; ++d) { float f = feat_s[i*DIM+d]; n2 = fmaf(f, f, n2); }
    rinv[i] = 1.0f / fmaxf(sqrtf(n2), 1e-8f);
  }
  __syncthreads();
  // label = (triu(sim) >= 0.75) & pair_valid
  for (int t = tid; t < KCAND*KCAND; t += 256) {
    int i = t / KCAND, j = t - i*KCAND;
    if (i <= j && valids[i] > 0.0f && valids[j] > 0.0f) {
      float dp = 0.0f;
      for (int d = 0; d < DIM; ++d) dp = fmaf(feat_s[i*DIM+d], feat_s[j*DIM+d], dp);
      float sim = dp * rinv[i] * rinv[j];
      if (sim >= 0.75f) atomicOr(&lab[i*4 + (j>>5)], 1u << (j & 31));
    }
  }
  __syncthreads();
  // column cumsum < 2 (dedup), keep = diag(cum) & valid
  for (int j = tid; j < KCAND; j += 256) {
    int c = 0;
    for (int i = 0; i < KCAND; ++i) {
      unsigned int l = (lab[i*4 + (j>>5)] >> (j & 31)) & 1u;
      c += (int)l;
      if (l && c < 2) atomicOr(&lkb[i*4 + (j>>5)], 1u << (j & 31));
      if (i == j) keeps[j] = (c < 2 && valids[j] > 0.0f) ? 1.0f : 0.0f;
    }
  }
  __syncthreads();
  for (int i = tid; i < KCAND; i += 256) {
    int cnt = 0;
    for (int w = 0; w < 4; ++w) cnt += __popc(lkb[i*4+w]);
    divis[i] = fmaxf((keeps[i] > 0.0f) ? (float)cnt : 0.0f, 1.0f);
  }
  __syncthreads();
  // meta = (label_k @ feat) / norm  (iterate set bits only)
  for (int t = tid; t < KCAND*DIM; t += 256) {
    int i = t >> 7, d = t & 127;
    float s = 0.0f;
    if (keeps[i] > 0.0f) {
      for (int w = 0; w < 4; ++w) {
        unsigned int m = lkb[i*4+w];
        while (m) {
          int j = (w << 5) + __ffs(m) - 1;
          m &= m - 1u;
          s += feat_s[j*DIM + d];
        }
      }
    }
    metag[t] = s / divis[i];
  }
  __syncthreads();
  for (int i = tid; i < KCAND; i += 256) {
    float n2 = 0.0f;
    for (int d = 0; d < DIM; ++d) { float f = metag[i*DIM+d]; n2 = fmaf(f, f, n2); }
    mnrm[i] = fmaxf(sqrtf(n2), 1e-8f);
  }
  __syncthreads();
  // mn transposed [d][r], rows 100..127 zero-padded
  for (int t = tid; t < RPAD*DIM; t += 256) {
    int d = t >> 7, r = t & 127;
    float v = 0.0f;
    if (r < KCAND) v = metag[r*DIM + d] / mnrm[r];
    mnt[d*RPAD + r] = v;
  }
  for (int r = tid; r < RPAD; r += 256) keepfg[r] = (r < KCAND) ? keeps[r] : 0.0f;
}

// ============ kernel 3/6: the GEMM sigmoid(mn @ enc) ============
// block: 256 threads = 16 tx (4 px each) x 16 ty (8 rows each); 128 rows x 64 px tile
// grid 800, each block 8 consecutive 64-px tiles. mn [d][r] staged in LDS (64 KB).
#define FMA4(a, m, e) { a.x = fmaf(m, e.x, a.x); a.y = fmaf(m, e.y, a.y); \
                        a.z = fmaf(m, e.z, a.z); a.w = fmaf(m, e.w, a.w); }

template<bool STATS>
__global__ __launch_bounds__(256, 2) void gemm_kernel(const float* __restrict__ enc,
                                                      char* __restrict__ ws,
                                                      float* __restrict__ out) {
  __shared__ float mn_s[RPAD * DIM];  // [d][r]
  const float* msrc = (const float*)(ws + (STATS ? WS_MNT : WS_MN2T));
  const float* ssrc = (const float*)(ws + (STATS ? WS_KEEPF : WS_SCALE2));
  double* cntd  = (double*)(ws + WS_CNT);
  double* ssumd = (double*)(ws + WS_SSUM);
  unsigned int* ds32 = (unsigned int*)(ws + WS_DS);

  int tid = threadIdx.x;
  int tx = tid & 15, ty = tid >> 4;
  for (int t = tid; t < RPAD*DIM; t += 256) mn_s[t] = msrc[t];
  float rowscale[8];
  #pragma unroll
  for (int ri = 0; ri < 8; ++ri) rowscale[ri] = ssrc[ty*8 + ri];
  __syncthreads();

  float cnt_acc[8], ssum_acc[8];
  #pragma unroll
  for (int ri = 0; ri < 8; ++ri) { cnt_acc[ri] = 0.0f; ssum_acc[ri] = 0.0f; }

  for (int k = 0; k < 8; ++k) {
    int t = blockIdx.x * 8 + k;
    int p0 = t * 64;
    const float* ep = enc + p0 + tx*4;
    float4 acc[8];
    #pragma unroll
    for (int ri = 0; ri < 8; ++ri) acc[ri] = make_float4(0.f, 0.f, 0.f, 0.f);
    #pragma unroll 4
    for (int d = 0; d < DIM; ++d) {
      float4 e = *(const float4*)(ep + (size_t)d * NPIX);
      const float4* mrow = (const float4*)(mn_s + (d << 7) + (ty << 3));
      float4 m0 = mrow[0], m1 = mrow[1];
      FMA4(acc[0], m0.x, e); FMA4(acc[1], m0.y, e);
      FMA4(acc[2], m0.z, e); FMA4(acc[3], m0.w, e);
      FMA4(acc[4], m1.x, e); FMA4(acc[5], m1.y, e);
      FMA4(acc[6], m1.z, e); FMA4(acc[7], m1.w, e);
    }
    if (STATS) {
      int y = t / 10;           // 10 tiles per 640-px image row
      int xw = t - y*10;
      bool yeven = (y & 1) == 0;
      int grp = ((tid & 63) >> 4) * 16;
      #pragma unroll
      for (int ri = 0; ri < 8; ++ri) {
        float4 a = acc[ri];
        float rs = rowscale[ri];
        float s0 = rs * (1.0f / (1.0f + expf(-a.x)));
        float s1 = rs * (1.0f / (1.0f + expf(-a.y)));
        float s2 = rs * (1.0f / (1.0f + expf(-a.z)));
        float s3 = rs * (1.0f / (1.0f + expf(-a.w)));
        bool b0 = s0 > 0.45f, b1 = s1 > 0.45f, b2 = s2 > 0.45f, b3 = s3 > 0.45f;
        cnt_acc[ri]  += (b0?1.f:0.f) + (b1?1.f:0.f) + (b2?1.f:0.f) + (b3?1.f:0.f);
        ssum_acc[ri] += (b0?s0:0.f) + (b1?s1:0.f) + (b2?s2:0.f) + (b3?s3:0.f);
        if (yeven) {
          unsigned long long v0 = __ballot(b0);
          unsigned long long v2 = __ballot(b2);
          if (tx == 0) {
            unsigned int w0 = (unsigned int)((v0 >> grp) & 0xFFFFull);
            unsigned int w2 = (unsigned int)((v2 >> grp) & 0xFFFFull);
            unsigned int word = spread16(w0) | (spread16(w2) << 1);
            int r = ty*8 + ri;
            ds32[r*DSW + (y >> 1)*10 + xw] = word;
          }
        }
      }
    } else {
      #pragma unroll
      for (int ri = 0; ri < 8; ++ri) {
        int r = ty*8 + ri;
        if (r < KCAND) {
          float4 a = acc[ri];
          float rs = rowscale[ri];
          float4 o;
          o.x = rs * (1.0f / (1.0f + expf(-a.x)));
          o.y = rs * (1.0f / (1.0f + expf(-a.y)));
          o.z = rs * (1.0f / (1.0f + expf(-a.z)));
          o.w = rs * (1.0f / (1.0f + expf(-a.w)));
          *(float4*)(out + (size_t)r * NPIX + p0 + tx*4) = o;
        }
      }
    }
  }
  if (STATS) {
    #pragma unroll
    for (int ri = 0; ri < 8; ++ri) {
      float cs = cnt_acc[ri], ss = ssum_acc[ri];
      #pragma unroll
      for (int off = 1; off < 16; off <<= 1) {
        cs += __shfl_xor(cs, off);
        ss += __shfl_xor(ss, off);
      }
      if (tx == 0) {
        int r = ty*8 + ri;
        atomicAdd(&cntd[r], (double)cs);
        atomicAdd(&ssumd[r], (double)ss);
      }
    }
  }
}

// ============ kernel 4: pairwise mask intersections (popcount over bitpacked ds) ============
__global__ __launch_bounds__(256) void inter_kernel(char* ws) {
  int i = blockIdx.y, j = blockIdx.x;
  if (j < i) return;
  const unsigned int* ds32 = (const unsigned int*)(ws + WS_DS);
  float* inter = (float*)(ws + WS_INTER);
  const unsigned int* a = ds32 + i * DSW;
  const unsigned int* b = ds32 + j * DSW;
  int s = 0;
  for (int w = threadIdx.x; w < DSW; w += 256) s += __popc(a[w] & b[w]);
  #pragma unroll
  for (int off = 32; off >= 1; off >>= 1) s += __shfl_xor(s, off);
  __shared__ int red[4];
  int lane = threadIdx.x & 63, wv = threadIdx.x >> 6;
  if (lane == 0) red[wv] = s;
  __syncthreads();
  if (threadIdx.x == 0) inter[i*KCAND + j] = (float)(red[0] + red[1] + red[2] + red[3]);
}

// ============ kernel 5: score/sort/matrix-NMS, small outputs, build mn2/scale2 ============
__global__ __launch_bounds__(256) void nms_kernel(char* ws, float* __restrict__ out) {
  float* topv   = (float*)(ws + WS_TOPV);
  float* keepfg = (float*)(ws + WS_KEEPF);
  double* cntd  = (double*)(ws + WS_CNT);
  double* ssumd = (double*)(ws + WS_SSUM);
  float* inter  = (float*)(ws + WS_INTER);
  float* mnt    = (float*)(ws + WS_MNT);
  float* mn2t   = (float*)(ws + WS_MN2T);
  float* scale2 = (float*)(ws + WS_SCALE2);

  __shared__ float iou_s[KCAND*KCAND];   // 40 KB
  __shared__ float sc0[KCAND], sc_s[KCAND], keep_s[KCAND], s2_s[KCAND];
  __shared__ float comp_[KCAND], k2f_[KCAND];
  __shared__ int order_[KCAND];

  int tid = threadIdx.x;
  for (int r = tid; r < KCAND; r += 256) {
    double c = cntd[r], s = ssumd[r];
    float seg = (float)(s / fmax(c, 1.0));
    sc0[r] = topv[r] * seg;
  }
  __syncthreads();
  // stable argsort(-sc) via exact rank
  for (int i = tid; i < KCAND; i += 256) {
    float v = sc0[i]; int rk = 0;
    for (int j = 0; j < KCAND; ++j) {
      float u = sc0[j];
      rk += (int)((u > v) || (u == v && j < i));
    }
    order_[rk] = i;
  }
  __syncthreads();
  for (int i = tid; i < KCAND; i += 256) {
    int oi = order_[i];
    sc_s[i]   = sc0[oi];
    keep_s[i] = keepfg[oi];
    s2_s[i]   = inter[oi*KCAND + oi];
  }
  __syncthreads();
  for (int t = tid; t < KCAND*KCAND; t += 256) {
    int i = t / KCAND, j = t - i*KCAND;
    float v = 0.0f;
    if (i < j) {
      int oi = order_[i], oj = order_[j];
      int a = min(oi, oj), b = max(oi, oj);
      float iv = inter[a*KCAND + b];
      float un = s2_s[i] + s2_s[j] - iv;
      v = iv / fmaxf(un, 1e-6f);
    }
    iou_s[t] = v;
  }
  __syncthreads();
  for (int i = tid; i < KCAND; i += 256) {
    float m = 0.0f;
    for (int r = 0; r < KCAND; ++r) m = fmaxf(m, iou_s[r*KCAND + i]);
    comp_[i] = m;
  }
  __syncthreads();
  for (int j = tid; j < KCAND; j += 256) {
    float mv = 3.4e38f;
    for (int i = 0; i < KCAND; ++i) {
      float io = iou_s[i*KCAND + j];
      float cm = comp_[i];
      float ratio = expf(-2.0f*io*io) / expf(-2.0f*cm*cm);
      mv = fminf(mv, ratio);
    }
    float sc2 = sc_s[j] * mv;
    bool k2 = (sc2 >= 0.05f) && (keep_s[j] > 0.5f);
    float kf = k2 ? 1.0f : 0.0f;
    k2f_[j] = kf;
    out[MOUT + j] = sc2 * kf;                 // scores
    out[MOUT + KCAND + j] = 0.0f;             // labels
    out[MOUT + 2*KCAND + j] = kf;             // keep
  }
  __syncthreads();
  for (int t = tid; t < RPAD*DIM; t += 256) {
    int d = t >> 7, r = t & 127;
    float v = 0.0f;
    if (r < KCAND) v = mnt[d*RPAD + order_[r]];
    mn2t[t] = v;
  }
  for (int r = tid; r < RPAD; r += 256) scale2[r] = (r < KCAND) ? k2f_[r] : 0.0f;
}

extern "C" void kernel_launch(void* const* d_in, const int* in_sizes, int n_in,
                              void* d_out, int out_size, void* d_ws, size_t ws_size,
                              hipStream_t stream) {
  const float* pred = (const float*)d_in[0];
  const float* emb  = (const float*)d_in[1];
  const float* enc  = (const float*)d_in[2];
  float* out = (float*)d_out;
  char* ws = (char*)d_ws;

  topk_kernel<<<dim3(1), dim3(256), 0, stream>>>(pred, ws);
  fuse_kernel<<<dim3(1), dim3(256), 0, stream>>>(emb, ws);
  gemm_kernel<true><<<dim3(800), dim3(256), 0, stream>>>(enc, ws, out);
  inter_kernel<<<dim3(100, 100), dim3(256), 0, stream>>>(ws);
  nms_kernel<<<dim3(1), dim3(256), 0, stream>>>(ws, out);
  gemm_kernel<false><<<dim3(800), dim3(256), 0, stream>>>(enc, ws, out);
}

// Round 2
// 1072.863 us; speedup vs baseline: 1.3334x; 1.3334x over previous
//
#include <hip/hip_runtime.h>
#include <math.h>

#define HW25600 25600
#define DIM 128
#define NPIX 409600
#define KCAND 100
#define RPAD 128
#define DSW 3200              // u32 words per downsampled row-mask (320*320 bits)
#define MOUT 40960000         // masks output elements (100*640*640)
#define NBLK 3200             // gemm blocks (one per 128-px tile)

// ---- workspace byte offsets ----
#define WS_TOPV    0          // f32[128] top_s
#define WS_TOPI    512        // i32[128] indices
#define WS_VALID   1024       // f32[128]
#define WS_KEEPF   1536       // f32[128]
#define WS_MNT     2048       // f32[128*128] mn, layout [d][r]
#define WS_META    67584      // f32[128*128] meta, layout [r][d]
#define WS_CNT     133120     // f64[128] seg pixel counts
#define WS_SSUM    134144     // f64[128] seg score sums
#define WS_INTER   135168     // f32[100*100] downsampled mask intersections
#define WS_MN2T    175168     // f32[128*128] permuted mn, layout [d][r]
#define WS_SCALE2  240704     // f32[128] final row scales (keep2)
#define WS_DS      241216     // u32[128*3200] bitpacked downsampled masks
#define WS_PART    1879616    // f32[3200*256] per-block stat partials (cnt|ssum)
// total: 5,156,416 bytes

__device__ __forceinline__ unsigned int spread16(unsigned int x) {
  x &= 0xFFFFu;
  x = (x | (x << 8)) & 0x00FF00FFu;
  x = (x | (x << 4)) & 0x0F0F0F0Fu;
  x = (x | (x << 2)) & 0x33333333u;
  x = (x | (x << 1)) & 0x55555555u;
  return x;
}

// ============ kernel 1: sigmoid + top-100 (radix histogram select) ============
__global__ __launch_bounds__(256) void topk_kernel(const float* __restrict__ pred, char* ws) {
  float* topv   = (float*)(ws + WS_TOPV);
  int*   topi   = (int*)(ws + WS_TOPI);
  float* validf = (float*)(ws + WS_VALID);

  __shared__ unsigned int hist[1024];
  __shared__ float cv[1024];
  __shared__ int ci[1024];
  __shared__ int scl[4];
  __shared__ unsigned int ncand;

  int tid = threadIdx.x;
  for (int b = tid; b < 1024; b += 256) hist[b] = 0;
  if (tid == 0) ncand = 0;
  __syncthreads();

  // pass A: histogram on bits[30:21] (sigmoid in (0,1) -> positive floats, monotone bits)
  for (int k = tid; k < HW25600; k += 256) {
    float s = 1.0f / (1.0f + expf(-pred[k]));
    unsigned int u = __float_as_uint(s);
    atomicAdd(&hist[u >> 21], 1u);
  }
  __syncthreads();
  if (tid == 0) {
    int c = 0, B = 0;
    for (int b = 1023; b >= 0; --b) {
      int h = (int)hist[b];
      if (c + h >= KCAND) { B = b; break; }
      c += h;
    }
    scl[0] = B; scl[1] = c;
  }
  __syncthreads();
  int B = scl[0], cAb = scl[1];
  __syncthreads();
  for (int b = tid; b < 1024; b += 256) hist[b] = 0;
  __syncthreads();
  // pass B: refine within bin B on bits[20:11]
  for (int k = tid; k < HW25600; k += 256) {
    float s = 1.0f / (1.0f + expf(-pred[k]));
    unsigned int u = __float_as_uint(s);
    if ((int)(u >> 21) == B) atomicAdd(&hist[(u >> 11) & 1023], 1u);
  }
  __syncthreads();
  if (tid == 0) {
    int target = KCAND - cAb;
    int c = 0, B2 = 0;
    for (int b = 1023; b >= 0; --b) {
      int h = (int)hist[b];
      if (c + h >= target) { B2 = b; break; }
      c += h;
    }
    scl[2] = B2;
  }
  __syncthreads();
  unsigned int thr = ((unsigned int)B << 21) | ((unsigned int)scl[2] << 11);
  // pass C: collect candidates (superset of top-100)
  for (int k = tid; k < HW25600; k += 256) {
    float s = 1.0f / (1.0f + expf(-pred[k]));
    unsigned int u = __float_as_uint(s);
    if (u >= thr) {
      unsigned int slot = atomicAdd(&ncand, 1u);
      if (slot < 1024u) { cv[slot] = s; ci[slot] = k; }
    }
  }
  __syncthreads();
  int nc = (int)(ncand < 1024u ? ncand : 1024u);
  // pass D: exact rank (descending value, ascending index on ties) == lax.top_k order
  for (int c = tid; c < nc; c += 256) {
    float v = cv[c]; int id = ci[c];
    int rk = 0;
    for (int o = 0; o < nc; ++o) {
      float u2 = cv[o]; int i2 = ci[o];
      rk += (int)((u2 > v) || (u2 == v && i2 < id));
    }
    if (rk < KCAND) {
      topv[rk] = v; topi[rk] = id;
      validf[rk] = (v > 0.75f) ? 1.0f : 0.0f;
    }
  }
  for (int r = tid; r < RPAD; r += 256)
    if (r >= KCAND) { topv[r] = 0.0f; topi[r] = 0; validf[r] = 0.0f; }
}

// ============ kernel 2: feat gather, cosine sim, dedup, meta kernels, mn ============
__global__ __launch_bounds__(256) void fuse_kernel(const float* __restrict__ emb, char* ws) {
  int*   topi   = (int*)(ws + WS_TOPI);
  float* validfg= (float*)(ws + WS_VALID);
  float* keepfg = (float*)(ws + WS_KEEPF);
  float* mnt    = (float*)(ws + WS_MNT);
  float* metag  = (float*)(ws + WS_META);

  __shared__ float feat_s[KCAND * DIM];      // 51200 B
  __shared__ unsigned int lab[KCAND * 4];
  __shared__ unsigned int lkb[KCAND * 4];
  __shared__ float rinv[KCAND];
  __shared__ float valids[KCAND];
  __shared__ float keeps[KCAND];
  __shared__ float divis[KCAND];
  __shared__ float mnrm[KCAND];

  int tid = threadIdx.x;
  for (int t = tid; t < KCAND * 4; t += 256) { lab[t] = 0u; lkb[t] = 0u; }
  for (int i = tid; i < KCAND; i += 256) valids[i] = validfg[i];
  for (int t = tid; t < KCAND * DIM; t += 256) {
    int i = t >> 7, d = t & 127;
    feat_s[t] = emb[d * HW25600 + topi[i]];
  }
  __syncthreads();
  for (int i = tid; i < KCAND; i += 256) {
    float n2 = 0.0f;
    for (int d = 0; d < DIM; ++d) { float f = feat_s[i*DIM+d]; n2 = fmaf(f, f, n2); }
    rinv[i] = 1.0f / fmaxf(sqrtf(n2), 1e-8f);
  }
  __syncthreads();
  // label = (triu(sim) >= 0.75) & pair_valid
  for (int t = tid; t < KCAND*KCAND; t += 256) {
    int i = t / KCAND, j = t - i*KCAND;
    if (i <= j && valids[i] > 0.0f && valids[j] > 0.0f) {
      float dp = 0.0f;
      for (int d = 0; d < DIM; ++d) dp = fmaf(feat_s[i*DIM+d], feat_s[j*DIM+d], dp);
      float sim = dp * rinv[i] * rinv[j];
      if (sim >= 0.75f) atomicOr(&lab[i*4 + (j>>5)], 1u << (j & 31));
    }
  }
  __syncthreads();
  // column cumsum < 2 (dedup), keep = diag(cum) & valid
  for (int j = tid; j < KCAND; j += 256) {
    int c = 0;
    for (int i = 0; i < KCAND; ++i) {
      unsigned int l = (lab[i*4 + (j>>5)] >> (j & 31)) & 1u;
      c += (int)l;
      if (l && c < 2) atomicOr(&lkb[i*4 + (j>>5)], 1u << (j & 31));
      if (i == j) keeps[j] = (c < 2 && valids[j] > 0.0f) ? 1.0f : 0.0f;
    }
  }
  __syncthreads();
  for (int i = tid; i < KCAND; i += 256) {
    int cnt = 0;
    for (int w = 0; w < 4; ++w) cnt += __popc(lkb[i*4+w]);
    divis[i] = fmaxf((keeps[i] > 0.0f) ? (float)cnt : 0.0f, 1.0f);
  }
  __syncthreads();
  // meta = (label_k @ feat) / norm  (iterate set bits only)
  for (int t = tid; t < KCAND*DIM; t += 256) {
    int i = t >> 7, d = t & 127;
    float s = 0.0f;
    if (keeps[i] > 0.0f) {
      for (int w = 0; w < 4; ++w) {
        unsigned int m = lkb[i*4+w];
        while (m) {
          int j = (w << 5) + __ffs(m) - 1;
          m &= m - 1u;
          s += feat_s[j*DIM + d];
        }
      }
    }
    metag[t] = s / divis[i];
  }
  __syncthreads();
  for (int i = tid; i < KCAND; i += 256) {
    float n2 = 0.0f;
    for (int d = 0; d < DIM; ++d) { float f = metag[i*DIM+d]; n2 = fmaf(f, f, n2); }
    mnrm[i] = fmaxf(sqrtf(n2), 1e-8f);
  }
  __syncthreads();
  // mn transposed [d][r], rows 100..127 zero-padded
  for (int t = tid; t < RPAD*DIM; t += 256) {
    int d = t >> 7, r = t & 127;
    float v = 0.0f;
    if (r < KCAND) v = metag[r*DIM + d] / mnrm[r];
    mnt[d*RPAD + r] = v;
  }
  for (int r = tid; r < RPAD; r += 256) keepfg[r] = (r < KCAND) ? keeps[r] : 0.0f;
}

// ============ kernel 3/7: GEMM sigmoid(mn @ enc) ============
// One 128-px tile per block; 256 threads = 32 tx (4 px) x 8 ty (16 rows).
// mn staged in d-chunks of 32 -> 16 KB LDS -> 4 blocks/CU residency.
#define FMA4(a, m, e) { a.x = fmaf(m, e.x, a.x); a.y = fmaf(m, e.y, a.y); \
                        a.z = fmaf(m, e.z, a.z); a.w = fmaf(m, e.w, a.w); }

template<bool STATS>
__global__ __launch_bounds__(256, 4) void gemm_kernel(const float* __restrict__ enc,
                                                      char* __restrict__ ws,
                                                      float* __restrict__ out) {
  __shared__ float mn_s[32 * RPAD];   // 16 KB: [d_chunk][128 rows]
  __shared__ float scale_s[RPAD];
  const float* msrc = (const float*)(ws + (STATS ? WS_MNT : WS_MN2T));
  const float* ssrc = (const float*)(ws + (STATS ? WS_KEEPF : WS_SCALE2));
  float* part = (float*)(ws + WS_PART);
  unsigned int* ds32 = (unsigned int*)(ws + WS_DS);

  int tid = threadIdx.x;
  int lane = tid & 63;
  int tx = tid & 31;          // 32 lanes * 4 px = 128 px
  int ty = tid >> 5;          // 8 groups * 16 rows = 128 rows
  int bx = blockIdx.x;
  int p0 = bx * 128 + tx * 4;
  if (tid < RPAD) scale_s[tid] = ssrc[tid];

  float4 acc[16];
  #pragma unroll
  for (int i = 0; i < 16; ++i) acc[i] = make_float4(0.f, 0.f, 0.f, 0.f);

  const float4* msrc4 = (const float4*)msrc;
  for (int c = 0; c < 4; ++c) {
    __syncthreads();
    #pragma unroll
    for (int t = 0; t < 4; ++t)
      ((float4*)mn_s)[tid + 256 * t] = msrc4[c * 1024 + tid + 256 * t];
    __syncthreads();
    const float* ep = enc + (size_t)(c * 32) * NPIX + p0;
    #pragma unroll 2
    for (int d = 0; d < 32; ++d) {
      float4 e = *(const float4*)(ep + (size_t)d * NPIX);
      const float4* mrow = (const float4*)(mn_s + (d << 7) + (ty << 4));
      float4 m0 = mrow[0], m1 = mrow[1], m2 = mrow[2], m3 = mrow[3];
      FMA4(acc[0],  m0.x, e); FMA4(acc[1],  m0.y, e);
      FMA4(acc[2],  m0.z, e); FMA4(acc[3],  m0.w, e);
      FMA4(acc[4],  m1.x, e); FMA4(acc[5],  m1.y, e);
      FMA4(acc[6],  m1.z, e); FMA4(acc[7],  m1.w, e);
      FMA4(acc[8],  m2.x, e); FMA4(acc[9],  m2.y, e);
      FMA4(acc[10], m2.z, e); FMA4(acc[11], m2.w, e);
      FMA4(acc[12], m3.x, e); FMA4(acc[13], m3.y, e);
      FMA4(acc[14], m3.z, e); FMA4(acc[15], m3.w, e);
    }
  }

  if (STATS) {
    int y = bx / 5, xw = bx - y * 5;   // image row, 128-px tile within row
    bool yeven = (y & 1) == 0;
    int grp = (lane >> 4) << 4;
    #pragma unroll
    for (int ri = 0; ri < 16; ++ri) {
      int r = (ty << 4) + ri;
      float rs = scale_s[r];
      float4 a = acc[ri];
      float s0 = rs * (1.0f / (1.0f + expf(-a.x)));
      float s1 = rs * (1.0f / (1.0f + expf(-a.y)));
      float s2 = rs * (1.0f / (1.0f + expf(-a.z)));
      float s3 = rs * (1.0f / (1.0f + expf(-a.w)));
      bool b0 = s0 > 0.45f, b1 = s1 > 0.45f, b2 = s2 > 0.45f, b3 = s3 > 0.45f;
      float cnt  = (b0?1.f:0.f) + (b1?1.f:0.f) + (b2?1.f:0.f) + (b3?1.f:0.f);
      float ssum = (b0?s0:0.f) + (b1?s1:0.f) + (b2?s2:0.f) + (b3?s3:0.f);
      if (yeven) {
        unsigned long long v0 = __ballot(b0);
        unsigned long long v2 = __ballot(b2);
        if ((lane & 15) == 0) {
          unsigned int w0 = (unsigned int)(v0 >> grp) & 0xFFFFu;
          unsigned int w2 = (unsigned int)(v2 >> grp) & 0xFFFFu;
          unsigned int word = spread16(w0) | (spread16(w2) << 1);
          ds32[r * DSW + (y >> 1) * 10 + xw * 2 + ((lane >> 4) & 1)] = word;
        }
      }
      #pragma unroll
      for (int off = 1; off <= 16; off <<= 1) {
        cnt  += __shfl_xor(cnt, off);
        ssum += __shfl_xor(ssum, off);
      }
      if ((lane & 31) == 0) {
        part[bx * 256 + r] = cnt;
        part[bx * 256 + RPAD + r] = ssum;
      }
    }
  } else {
    #pragma unroll
    for (int ri = 0; ri < 16; ++ri) {
      int r = (ty << 4) + ri;
      if (r < KCAND) {
        float rs = scale_s[r];
        float4 a = acc[ri];
        float4 o;
        o.x = rs * (1.0f / (1.0f + expf(-a.x)));
        o.y = rs * (1.0f / (1.0f + expf(-a.y)));
        o.z = rs * (1.0f / (1.0f + expf(-a.z)));
        o.w = rs * (1.0f / (1.0f + expf(-a.w)));
        *(float4*)(out + (size_t)r * NPIX + p0) = o;
      }
    }
  }
}

// ============ kernel 4: deterministic f64 reduce of per-block stat partials ============
__global__ __launch_bounds__(256) void stats_reduce_kernel(char* ws) {
  const float* part = (const float*)(ws + WS_PART);
  double* cntd  = (double*)(ws + WS_CNT);
  double* ssumd = (double*)(ws + WS_SSUM);
  __shared__ double cs_[256], ss_[256];
  int tid = threadIdx.x;
  int r = blockIdx.x;
  double c = 0.0, s = 0.0;
  for (int b = tid; b < NBLK; b += 256) {
    c += (double)part[b * 256 + r];
    s += (double)part[b * 256 + RPAD + r];
  }
  cs_[tid] = c; ss_[tid] = s;
  __syncthreads();
  for (int o = 128; o >= 1; o >>= 1) {
    if (tid < o) { cs_[tid] += cs_[tid + o]; ss_[tid] += ss_[tid + o]; }
    __syncthreads();
  }
  if (tid == 0) { cntd[r] = cs_[0]; ssumd[r] = ss_[0]; }
}

// ============ kernel 5: pairwise mask intersections (popcount over bitpacked ds) ============
__global__ __launch_bounds__(256) void inter_kernel(char* ws) {
  int i = blockIdx.y, j = blockIdx.x;
  if (j < i) return;
  const unsigned int* ds32 = (const unsigned int*)(ws + WS_DS);
  float* inter = (float*)(ws + WS_INTER);
  const unsigned int* a = ds32 + i * DSW;
  const unsigned int* b = ds32 + j * DSW;
  int s = 0;
  for (int w = threadIdx.x; w < DSW; w += 256) s += __popc(a[w] & b[w]);
  #pragma unroll
  for (int off = 32; off >= 1; off >>= 1) s += __shfl_xor(s, off);
  __shared__ int red[4];
  int lane = threadIdx.x & 63, wv = threadIdx.x >> 6;
  if (lane == 0) red[wv] = s;
  __syncthreads();
  if (threadIdx.x == 0) inter[i*KCAND + j] = (float)(red[0] + red[1] + red[2] + red[3]);
}

// ============ kernel 6: score/sort/matrix-NMS, small outputs, build mn2/scale2 ============
__global__ __launch_bounds__(256) void nms_kernel(char* ws, float* __restrict__ out) {
  float* topv   = (float*)(ws + WS_TOPV);
  float* keepfg = (float*)(ws + WS_KEEPF);
  double* cntd  = (double*)(ws + WS_CNT);
  double* ssumd = (double*)(ws + WS_SSUM);
  float* inter  = (float*)(ws + WS_INTER);
  float* mnt    = (float*)(ws + WS_MNT);
  float* mn2t   = (float*)(ws + WS_MN2T);
  float* scale2 = (float*)(ws + WS_SCALE2);

  __shared__ float iou_s[KCAND*KCAND];   // 40 KB
  __shared__ float sc0[KCAND], sc_s[KCAND], keep_s[KCAND], s2_s[KCAND];
  __shared__ float comp_[KCAND], k2f_[KCAND];
  __shared__ int order_[KCAND];

  int tid = threadIdx.x;
  for (int r = tid; r < KCAND; r += 256) {
    double c = cntd[r], s = ssumd[r];
    float seg = (float)(s / fmax(c, 1.0));
    sc0[r] = topv[r] * seg;
  }
  __syncthreads();
  // stable argsort(-sc) via exact rank
  for (int i = tid; i < KCAND; i += 256) {
    float v = sc0[i]; int rk = 0;
    for (int j = 0; j < KCAND; ++j) {
      float u = sc0[j];
      rk += (int)((u > v) || (u == v && j < i));
    }
    order_[rk] = i;
  }
  __syncthreads();
  for (int i = tid; i < KCAND; i += 256) {
    int oi = order_[i];
    sc_s[i]   = sc0[oi];
    keep_s[i] = keepfg[oi];
    s2_s[i]   = inter[oi*KCAND + oi];
  }
  __syncthreads();
  for (int t = tid; t < KCAND*KCAND; t += 256) {
    int i = t / KCAND, j = t - i*KCAND;
    float v = 0.0f;
    if (i < j) {
      int oi = order_[i], oj = order_[j];
      int a = min(oi, oj), b = max(oi, oj);
      float iv = inter[a*KCAND + b];
      float un = s2_s[i] + s2_s[j] - iv;
      v = iv / fmaxf(un, 1e-6f);
    }
    iou_s[t] = v;
  }
  __syncthreads();
  for (int i = tid; i < KCAND; i += 256) {
    float m = 0.0f;
    for (int r = 0; r < KCAND; ++r) m = fmaxf(m, iou_s[r*KCAND + i]);
    comp_[i] = m;
  }
  __syncthreads();
  for (int j = tid; j < KCAND; j += 256) {
    float mv = 3.4e38f;
    for (int i = 0; i < KCAND; ++i) {
      float io = iou_s[i*KCAND + j];
      float cm = comp_[i];
      float ratio = expf(-2.0f*io*io) / expf(-2.0f*cm*cm);
      mv = fminf(mv, ratio);
    }
    float sc2 = sc_s[j] * mv;
    bool k2 = (sc2 >= 0.05f) && (keep_s[j] > 0.5f);
    float kf = k2 ? 1.0f : 0.0f;
    k2f_[j] = kf;
    out[MOUT + j] = sc2 * kf;                 // scores
    out[MOUT + KCAND + j] = 0.0f;             // labels
    out[MOUT + 2*KCAND + j] = kf;             // keep
  }
  __syncthreads();
  for (int t = tid; t < RPAD*DIM; t += 256) {
    int d = t >> 7, r = t & 127;
    float v = 0.0f;
    if (r < KCAND) v = mnt[d*RPAD + order_[r]];
    mn2t[t] = v;
  }
  for (int r = tid; r < RPAD; r += 256) scale2[r] = (r < KCAND) ? k2f_[r] : 0.0f;
}

extern "C" void kernel_launch(void* const* d_in, const int* in_sizes, int n_in,
                              void* d_out, int out_size, void* d_ws, size_t ws_size,
                              hipStream_t stream) {
  const float* pred = (const float*)d_in[0];
  const float* emb  = (const float*)d_in[1];
  const float* enc  = (const float*)d_in[2];
  float* out = (float*)d_out;
  char* ws = (char*)d_ws;

  topk_kernel<<<dim3(1), dim3(256), 0, stream>>>(pred, ws);
  fuse_kernel<<<dim3(1), dim3(256), 0, stream>>>(emb, ws);
  gemm_kernel<true><<<dim3(NBLK), dim3(256), 0, stream>>>(enc, ws, out);
  stats_reduce_kernel<<<dim3(RPAD), dim3(256), 0, stream>>>(ws);
  inter_kernel<<<dim3(100, 100), dim3(256), 0, stream>>>(ws);
  nms_kernel<<<dim3(1), dim3(256), 0, stream>>>(ws, out);
  gemm_kernel<false><<<dim3(NBLK), dim3(256), 0, stream>>>(enc, ws, out);
}